// Round 6
// baseline (120.328 us; speedup 1.0000x reference)
//
#include <hip/hip_runtime.h>

typedef unsigned short ushort_t;
typedef __attribute__((ext_vector_type(8))) short short8;
typedef __attribute__((ext_vector_type(4))) short short4v;
typedef __attribute__((ext_vector_type(2))) float float2v;
typedef __attribute__((ext_vector_type(4))) float float4v;

#define Bn 32
#define Nn 2048
#define Cn 8
#define Fn 128
#define On 128
#define Kn 384   // 3*F
#define MT 16    // rows per tile
#define NT 8     // tiles per block (block covers 128 rows)
#define LDSK 392 // padded row stride in shorts (784 B)
#define NBLK 512 // blocks; 512 threads each (8 waves)

// float -> bf16 bits, round-to-nearest-even
__device__ __forceinline__ ushort_t f2bf(float x) {
  unsigned u = __float_as_uint(x);
  u += 0x7fffu + ((u >> 16) & 1u);
  return (ushort_t)(u >> 16);
}

// Pack concat(w_t, w_r, w_l) in MFMA B-fragment order:
// fragment q (0..7), step ks (0..11): element ((q*12+ks)*64 + lane)*8 + j
// holds W[k][col] with col = q*16 + (lane&15), k = (lane>>4)*8 + ks*32 + j.
__global__ void prep_w_kernel(const float* __restrict__ w_t,
                              const float* __restrict__ w_l,
                              const float* __restrict__ w_r,
                              ushort_t* __restrict__ wsw) {
  int t = blockIdx.x * blockDim.x + threadIdx.x; // one short8 per thread
  if (t >= 6144) return;                         // 6144*8 = 49152 elements
  int lane = t & 63;
  int r = t >> 6;  // 0..95
  int ks = r % 12;
  int q = r / 12;  // 0..7
  int col = q * 16 + (lane & 15);
  int kbase = ((lane >> 4) * 8) + ks * 32;
  ushort_t* dst = wsw + (size_t)t * 8;
#pragma unroll
  for (int j = 0; j < 8; ++j) {
    int k = kbase + j;
    const float* src = (k < Fn) ? w_t : (k < 2 * Fn) ? w_r : w_l;
    int f = k & (Fn - 1);
    dst[j] = f2bf(src[f * On + col]);
  }
}

// Per-row coefficient precompute: coef[row][2c] = cr_c, [2c+1] = cl_c.
// Removes the ~40-VALU/row redundant coef math from the main kernel.
__global__ void prep_coef_kernel(const int* __restrict__ children,
                                 float* __restrict__ coef) {
  int g = blockIdx.x * blockDim.x + threadIdx.x;
  if (g >= Bn * Nn) return;
  const int4* chv = (const int4*)(children + (size_t)g * Cn);
  int4 ca = chv[0], cb = chv[1];
  int idx[Cn] = {ca.x, ca.y, ca.z, ca.w, cb.x, cb.y, cb.z, cb.w};
  int ns = 0;
#pragma unroll
  for (int c = 0; c < Cn; ++c) ns += (idx[c] != 0);
  const float denom = (ns > 1) ? (float)(ns - 1) : 1.0f;
  float o[16];
#pragma unroll
  for (int c = 0; c < Cn; ++c) {
    float m = (idx[c] != 0) ? 1.0f : 0.0f;
    float cr0 = (ns == 1) ? ((c == 0) ? 0.5f : 0.0f) : ((float)c / denom);
    float cr = cr0 * m;
    o[2 * c] = cr;
    o[2 * c + 1] = (1.0f - cr) * m;
  }
  float4v* dst = (float4v*)(coef + (size_t)g * 16);
#pragma unroll
  for (int j = 0; j < 4; ++j) {
    float4v v = {o[4 * j], o[4 * j + 1], o[4 * j + 2], o[4 * j + 3]};
    dst[j] = v;
  }
}

__global__ __launch_bounds__(512, 4)
void tree_conv_kernel(const float* __restrict__ nodes,
                      const int* __restrict__ children,
                      const float* __restrict__ coefb,
                      const ushort_t* __restrict__ wsw,
                      const float* __restrict__ bias,
                      float* __restrict__ out) {
  __shared__ __align__(16) ushort_t agg[2][MT * LDSK];  // ping-pong, 24.5 KiB
  __shared__ __align__(16) int ch_lds[NT * MT * Cn];    // 4 KiB
  __shared__ __align__(16) float cf_lds[NT * MT * 16];  // 8 KiB

  const int tid = threadIdx.x;
  const int wave = tid >> 6;  // 0..7, owns cols [wave*16, wave*16+16)
  const int lane = tid & 63;
  const int l15 = lane & 15;
  const int quad = lane >> 4;
  const int grp = tid >> 5;  // 0..15: row within tile
  const int ln = tid & 31;   // float4 chunk of F

  // XCD-locality swizzle: XCD k (round-robin %8) owns batches 4k..4k+3.
  const int sb = ((blockIdx.x & 7) << 6) | (blockIdx.x >> 3);
  const int rb0 = sb * (MT * NT);       // first of 128 rows (batch-aligned)
  const int batch_base = rb0 & ~(Nn - 1);

  // ---- stage this block's children + coefs into LDS (coalesced, once) ----
  if (tid < 256)
    ((int4*)ch_lds)[tid] = ((const int4*)(children + (size_t)rb0 * Cn))[tid];
  ((float4v*)cf_lds)[tid] = ((const float4v*)(coefb + (size_t)rb0 * 16))[tid];

  // ---- B fragments: once per wave, held in 48 VGPRs for all 8 tiles ----
  short8 bfrag[12];
  {
    const short8* bp = (const short8*)wsw + (wave * 12) * 64 + lane;
#pragma unroll
    for (int ks = 0; ks < 12; ++ks) bfrag[ks] = bp[ks * 64];
  }
  const int col = wave * 16 + l15;
  const float bb = bias[col];

  __syncthreads();  // LDS staging visible

  float4v gv[Cn], sv, cf[4];

  auto issue = [&](int t) {
    const int lrow = t * MT + grp;
    int4 ia = ((const int4*)(ch_lds + lrow * Cn))[0];  // LDS broadcast
    int4 ib = ((const int4*)(ch_lds + lrow * Cn))[1];
    const float4v* cp = (const float4v*)(cf_lds + lrow * 16);
    cf[0] = cp[0]; cf[1] = cp[1]; cf[2] = cp[2]; cf[3] = cp[3];
    const int g = rb0 + lrow;
    sv = *((const float4v*)(nodes + (size_t)g * Fn) + ln);
    int idx[Cn] = {ia.x, ia.y, ia.z, ia.w, ib.x, ib.y, ib.z, ib.w};
#pragma unroll
    for (int c = 0; c < Cn; ++c) {
      // clamp: replay-safe even with poisoned inputs; no-op for valid data
      const int r = batch_base + (idx[c] & (Nn - 1));
      gv[c] = *((const float4v*)(nodes + (size_t)r * Fn) + ln);
    }
  };

  auto combine = [&](int buf) {
    // (r,l) pairs in float2 -> v_pk_fma_f32 (halves FMA instruction count)
    float2v rl0 = {0.f, 0.f}, rl1 = {0.f, 0.f}, rl2 = {0.f, 0.f}, rl3 = {0.f, 0.f};
#pragma unroll
    for (int c = 0; c < Cn; ++c) {
      const float2v cc = {cf[c >> 1][(c & 1) * 2], cf[c >> 1][(c & 1) * 2 + 1]};
      const float4v v = gv[c];
      rl0 += (float2v){v.x, v.x} * cc;
      rl1 += (float2v){v.y, v.y} * cc;
      rl2 += (float2v){v.z, v.z} * cc;
      rl3 += (float2v){v.w, v.w} * cc;
    }
    ushort_t* arow = agg[buf] + grp * LDSK;
    short4v ps = {(short)f2bf(sv.x), (short)f2bf(sv.y),
                  (short)f2bf(sv.z), (short)f2bf(sv.w)};
    short4v pr = {(short)f2bf(rl0.x), (short)f2bf(rl1.x),
                  (short)f2bf(rl2.x), (short)f2bf(rl3.x)};
    short4v pl = {(short)f2bf(rl0.y), (short)f2bf(rl1.y),
                  (short)f2bf(rl2.y), (short)f2bf(rl3.y)};
    *(short4v*)(arow + ln * 4) = ps;
    *(short4v*)(arow + Fn + ln * 4) = pr;
    *(short4v*)(arow + 2 * Fn + ln * 4) = pl;
  };

  issue(0);
  combine(0);

  for (int t = 0; t < NT; ++t) {
    __syncthreads();  // agg[t&1] complete; previous phase-B readers done
    if (t + 1 < NT) issue(t + 1);  // gathers fly under the MFMAs below

    const ushort_t* ar = agg[t & 1] + l15 * LDSK + quad * 8;
    float4v acc = {0.f, 0.f, 0.f, 0.f};
#pragma unroll
    for (int ks = 0; ks < 12; ++ks) {
      short8 af = *(const short8*)(ar + ks * 32);
      acc = __builtin_amdgcn_mfma_f32_16x16x32_bf16(af, bfrag[ks], acc, 0, 0, 0);
    }
    const int grow = rb0 + t * MT + quad * 4;
#pragma unroll
    for (int r2 = 0; r2 < 4; ++r2)
      out[(size_t)(grow + r2) * On + col] = fmaxf(acc[r2] + bb, 0.f);

    if (t + 1 < NT) combine((t + 1) & 1);  // waits its gathers; writes other buf
  }
}

extern "C" void kernel_launch(void* const* d_in, const int* in_sizes, int n_in,
                              void* d_out, int out_size, void* d_ws, size_t ws_size,
                              hipStream_t stream) {
  const float* nodes = (const float*)d_in[0];
  const int* children = (const int*)d_in[1];
  const float* w_t = (const float*)d_in[2];
  const float* w_l = (const float*)d_in[3];
  const float* w_r = (const float*)d_in[4];
  const float* bias = (const float*)d_in[5];
  float* out = (float*)d_out;

  float* coefb = (float*)d_ws;                               // 4 MiB
  ushort_t* wsw = (ushort_t*)((char*)d_ws + (4u << 20));     // 96 KiB

  prep_w_kernel<<<24, 256, 0, stream>>>(w_t, w_l, w_r, wsw);
  prep_coef_kernel<<<(Bn * Nn) / 256, 256, 0, stream>>>(children, coefb);
  tree_conv_kernel<<<NBLK, 512, 0, stream>>>(nodes, children, coefb, wsw, bias, out);
}